// Round 12
// baseline (353.473 us; speedup 1.0000x reference)
//
#include <hip/hip_runtime.h>

typedef float f32x4 __attribute__((ext_vector_type(4)));
typedef short s16x8 __attribute__((ext_vector_type(8)));
typedef unsigned int u32x4 __attribute__((ext_vector_type(4)));
typedef unsigned short u16;
typedef unsigned int u32;

#define QK_SCALE 0.17677669529663687f  // 32^-0.5

__device__ __forceinline__ u16 f2bf(float f) {
    unsigned u = __builtin_bit_cast(unsigned, f);
    u = (u + 0x7fffu + ((u >> 16) & 1u)) >> 16;
    return (u16)u;
}
__device__ __forceinline__ u32 pk2(float lo, float hi) {
    return (u32)f2bf(lo) | ((u32)f2bf(hi) << 16);
}

// C-frag(pair) -> operand-frag conversion:
// dst lane (c,g) elem e needs M[t=c][u=8g+e]; src lane (c, 2(g&1)+(e>>2)),
// utile=g>>1, j=e&3.  r0/r1 = packed (j0,j1)/(j2,j3) words per utile.
__device__ __forceinline__ s16x8 frag4(u32 r0u0, u32 r1u0, u32 r0u1, u32 r1u1,
                                       int aA, int aB, bool lo) {
    u32x4 w;
    u32 a, bq;
    a  = (u32)__builtin_amdgcn_ds_bpermute(aA, (int)r0u0);
    bq = (u32)__builtin_amdgcn_ds_bpermute(aA, (int)r0u1);
    w[0] = lo ? a : bq;
    a  = (u32)__builtin_amdgcn_ds_bpermute(aA, (int)r1u0);
    bq = (u32)__builtin_amdgcn_ds_bpermute(aA, (int)r1u1);
    w[1] = lo ? a : bq;
    a  = (u32)__builtin_amdgcn_ds_bpermute(aB, (int)r0u0);
    bq = (u32)__builtin_amdgcn_ds_bpermute(aB, (int)r0u1);
    w[2] = lo ? a : bq;
    a  = (u32)__builtin_amdgcn_ds_bpermute(aB, (int)r1u0);
    bq = (u32)__builtin_amdgcn_ds_bpermute(aB, (int)r1u1);
    w[3] = lo ? a : bq;
    return __builtin_bit_cast(s16x8, w);
}

// ---- workspace byte offsets ----
// wqkvC2: 196608 bf16 = 393216 B   [h8][f6 = t3*dt2][ks8][lane64][e8]  (A-frags of W for W·X^T)
// projwC:  65536 bf16 = 131072 B   [nt16][ks8][lane64][e8]
// bmC2  : 2097152 bf16 = 4 MB      [wi64][h8][ntQ4][mtK4][lane64][j4]  (bias+mask, St frag order)
#define WS_PROJW 393216
#define WS_BMC   524288

__global__ void prep(const float* __restrict__ qkv_w, const float* __restrict__ proj_w,
                     const float* __restrict__ bias_table, const int* __restrict__ rel_index,
                     const float* __restrict__ mask,
                     u16* __restrict__ wqkvC2, u16* __restrict__ projwC,
                     u16* __restrict__ bmC2) {
    int i = blockIdx.x * 256 + threadIdx.x;
    if (i < 196608) {                       // qkv weights as A-frags of W·X^T
        int e = i & 7, lane = (i >> 3) & 63, ks = (i >> 9) & 7, dt = (i >> 12) & 1;
        int i2 = i >> 13, t = i2 % 3, h = i2 / 3;
        int c = lane & 15, g = lane >> 4;
        wqkvC2[i] = f2bf(qkv_w[(t * 256 + h * 32 + dt * 16 + c) * 256 + ks * 32 + g * 8 + e]);
    }
    if (i < 65536) {                        // proj weights -> fragment order
        int e = i & 7, lane = (i >> 3) & 63, ks = (i >> 9) & 7, nt = (i >> 12) & 15;
        int c = lane & 15, g = lane >> 4;
        projwC[i] = f2bf(proj_w[(nt * 16 + c) * 256 + ks * 32 + g * 8 + e]);
    }
    {                                       // merged bias+mask, bf16, St C-frag order
        int j = i & 3, lane = (i >> 2) & 63, mtK = (i >> 8) & 3, ntQ = (i >> 10) & 3;
        int h = (i >> 12) & 7, wi = i >> 15;
        int c = lane & 15, g = lane >> 4;
        int q = ntQ * 16 + c, k = mtK * 16 + g * 4 + j;
        float v;
        if (k < 49) v = (q < 49) ? bias_table[rel_index[q * 49 + k] * 8 + h]
                                   + mask[wi * 2401 + q * 49 + k]
                                 : 0.f;
        else        v = -1e30f;             // pad-column mask folded in
        bmC2[i] = f2bf(v);
    }
}

// ---- LDS (u16 offsets), total 31368 u16 = 62,736 B -> 2 blocks/CU, 16 waves/CU ----
// XS  : [0, 12936)  49 rows x 264  (x window, bf16)
// VT  : 12936 + wv*2304, [d32][tok72-pad] per wave (8 waves)
// OUTS: [0, 12936)  overlaps XS after barrier
__global__ __launch_bounds__(512, 4)
void swin_attn(const float* __restrict__ x,
               const float* __restrict__ qkv_b,
               const float* __restrict__ proj_b,
               const u16* __restrict__ wqkvC2,
               const u16* __restrict__ projwC,
               const u16* __restrict__ bmC2,
               float* __restrict__ out) {
    __shared__ __align__(16) u16 sm[31368];
    const int b = blockIdx.x, tid = threadIdx.x;
    const int wv = tid >> 6, lane = tid & 63, g = lane >> 4, c = lane & 15;
    const int wi = b & 63;
    const int h = wv;                     // one head per wave
    const int VTb = 12936 + wv * 2304;
    const float* xw = x + (size_t)b * 12544;

    // stage x window (bf16), rows 0..48
    for (int i = tid; i < 49 * 64; i += 512) {
        int row = i >> 6, q4 = i & 63;
        float4 v = ((const float4*)xw)[i];
        ushort4 s;
        s.x = f2bf(v.x); s.y = f2bf(v.y); s.z = f2bf(v.z); s.w = f2bf(v.w);
        *(ushort4*)&sm[row * 264 + q4 * 4] = s;
    }
    __syncthreads();

    const int addrA = ((lane & 15) + ((lane & 16) << 1)) << 2;  // src lane c+32*(g&1)
    const int addrB = addrA + 64;                               // +16 lanes
    const bool lo = lane < 32;                                  // utile = g>>1
    const s16x8 zfrag = {0, 0, 0, 0, 0, 0, 0, 0};

    // ---- QKV as W·X^T in three single-t passes (acc 32 + wf 16 + Xf 16 live) ----
    u32 qp[4][2][2], kp[4][2][2];
#pragma unroll
    for (int t = 0; t < 3; ++t) {
        f32x4 acc[2][4];
#pragma unroll
        for (int dt = 0; dt < 2; ++dt)
#pragma unroll
            for (int tt = 0; tt < 4; ++tt) acc[dt][tt] = f32x4{0.f, 0.f, 0.f, 0.f};

        s16x8 wf[2][2];
#pragma unroll
        for (int dt = 0; dt < 2; ++dt)
            wf[0][dt] = *(const s16x8*)&wqkvC2[(((h * 6 + t * 2 + dt) * 8 + 0) * 64 + lane) * 8];
#pragma unroll
        for (int ks = 0; ks < 8; ++ks) {
            if (ks < 7) {
#pragma unroll
                for (int dt = 0; dt < 2; ++dt)
                    wf[(ks + 1) & 1][dt] =
                        *(const s16x8*)&wqkvC2[(((h * 6 + t * 2 + dt) * 8 + (ks + 1)) * 64 + lane) * 8];
            }
            s16x8 Xf[4];
#pragma unroll
            for (int tt = 0; tt < 4; ++tt)
                Xf[tt] = *(const s16x8*)&sm[(tt * 16 + c) * 264 + ks * 32 + g * 8];
            if (c > 0) Xf[3] = zfrag;      // tokens 49..63 zero
#pragma unroll
            for (int dt = 0; dt < 2; ++dt)
#pragma unroll
                for (int tt = 0; tt < 4; ++tt)
                    acc[dt][tt] = __builtin_amdgcn_mfma_f32_16x16x32_bf16(wf[ks & 1][dt], Xf[tt], acc[dt][tt], 0, 0, 0);
        }
        // bias; pack Qt/Kt to regs; Vt -> VT LDS
#pragma unroll
        for (int dt = 0; dt < 2; ++dt) {
            f32x4 bv = *(const f32x4*)&qkv_b[t * 256 + h * 32 + dt * 16 + g * 4];
#pragma unroll
            for (int tt = 0; tt < 4; ++tt) {
                float v0 = acc[dt][tt][0] + bv[0];
                float v1 = acc[dt][tt][1] + bv[1];
                float v2 = acc[dt][tt][2] + bv[2];
                float v3 = acc[dt][tt][3] + bv[3];
                if (t == 0) {
                    qp[tt][dt][0] = pk2(v0 * QK_SCALE, v1 * QK_SCALE);
                    qp[tt][dt][1] = pk2(v2 * QK_SCALE, v3 * QK_SCALE);
                } else if (t == 1) {
                    kp[tt][dt][0] = pk2(v0, v1);
                    kp[tt][dt][1] = pk2(v2, v3);
                } else {
                    sm[VTb + (dt * 16 + g * 4 + 0) * 72 + tt * 16 + c] = f2bf(v0);
                    sm[VTb + (dt * 16 + g * 4 + 1) * 72 + tt * 16 + c] = f2bf(v1);
                    sm[VTb + (dt * 16 + g * 4 + 2) * 72 + tt * 16 + c] = f2bf(v2);
                    sm[VTb + (dt * 16 + g * 4 + 3) * 72 + tt * 16 + c] = f2bf(v3);
                }
            }
        }
    }

    // ---- Kf once (kp dies); V frags hoisted to regs; qp kept for per-ntQ Qf ----
    s16x8 Kf[4];
#pragma unroll
    for (int mt = 0; mt < 4; ++mt)
        Kf[mt] = frag4(kp[mt][0][0], kp[mt][0][1], kp[mt][1][0], kp[mt][1][1], addrA, addrB, lo);
    s16x8 Vr[2][2];
#pragma unroll
    for (int ks2 = 0; ks2 < 2; ++ks2)
#pragma unroll
        for (int ndt = 0; ndt < 2; ++ndt)
            Vr[ks2][ndt] = *(const s16x8*)&sm[VTb + (ndt * 16 + c) * 72 + ks2 * 32 + g * 8];

    // bm for ntQ=0
    u32 bc0[4], bc1[4];
#pragma unroll
    for (int mtK = 0; mtK < 4; ++mtK) {
        const u32* bp = (const u32*)&bmC2[((((wi * 8 + h) * 4 + 0) * 4 + mtK) * 64 + lane) * 4];
        bc0[mtK] = bp[0];
        bc1[mtK] = bp[1];
    }

    // ---- streamed attention: per q-tile {Qf, St, softmax, pack, PV} ----
    u32 opk[4][2][2];
#pragma unroll
    for (int ntQ = 0; ntQ < 4; ++ntQ) {
        // prefetch next tile's bias/mask
        u32 bn0[4], bn1[4];
        if (ntQ < 3) {
#pragma unroll
            for (int mtK = 0; mtK < 4; ++mtK) {
                const u32* bp = (const u32*)&bmC2[((((wi * 8 + h) * 4 + (ntQ + 1)) * 4 + mtK) * 64 + lane) * 4];
                bn0[mtK] = bp[0];
                bn1[mtK] = bp[1];
            }
        }
        s16x8 Qfc = frag4(qp[ntQ][0][0], qp[ntQ][0][1], qp[ntQ][1][0], qp[ntQ][1][1], addrA, addrB, lo);
        f32x4 lvc[4];
#pragma unroll
        for (int mtK = 0; mtK < 4; ++mtK) {
            f32x4 z = {0.f, 0.f, 0.f, 0.f};
            lvc[mtK] = __builtin_amdgcn_mfma_f32_16x16x32_bf16(Kf[mtK], Qfc, z, 0, 0, 0);
        }
        float m = -1e30f;
#pragma unroll
        for (int mtK = 0; mtK < 4; ++mtK) {
            u32 w0 = bc0[mtK], w1 = bc1[mtK];
            float b0 = __builtin_bit_cast(float, w0 << 16);
            float b1 = __builtin_bit_cast(float, w0 & 0xffff0000u);
            float b2 = __builtin_bit_cast(float, w1 << 16);
            float b3 = __builtin_bit_cast(float, w1 & 0xffff0000u);
            float v0 = lvc[mtK][0] + b0;
            float v1 = lvc[mtK][1] + b1;
            float v2 = lvc[mtK][2] + b2;
            float v3 = lvc[mtK][3] + b3;
            lvc[mtK][0] = v0; lvc[mtK][1] = v1;
            lvc[mtK][2] = v2; lvc[mtK][3] = v3;
            m = fmaxf(m, fmaxf(fmaxf(v0, v1), fmaxf(v2, v3)));
        }
        m = fmaxf(m, __shfl_xor(m, 16));
        m = fmaxf(m, __shfl_xor(m, 32));
        float s = 0.f;
#pragma unroll
        for (int mtK = 0; mtK < 4; ++mtK)
#pragma unroll
            for (int j = 0; j < 4; ++j) {
                float e = __expf(lvc[mtK][j] - m);
                lvc[mtK][j] = e;
                s += e;
            }
        s += __shfl_xor(s, 16);
        s += __shfl_xor(s, 32);
        float is = 1.0f / s;
        u32 ppc[4][2];
#pragma unroll
        for (int mtK = 0; mtK < 4; ++mtK) {
            ppc[mtK][0] = pk2(lvc[mtK][0] * is, lvc[mtK][1] * is);
            ppc[mtK][1] = pk2(lvc[mtK][2] * is, lvc[mtK][3] * is);
        }
        // PV for this q-tile
        f32x4 o[2] = {{0.f, 0.f, 0.f, 0.f}, {0.f, 0.f, 0.f, 0.f}};
#pragma unroll
        for (int ks2 = 0; ks2 < 2; ++ks2) {
            s16x8 Pf = frag4(ppc[2 * ks2][0], ppc[2 * ks2][1],
                             ppc[2 * ks2 + 1][0], ppc[2 * ks2 + 1][1], addrA, addrB, lo);
#pragma unroll
            for (int ndt = 0; ndt < 2; ++ndt)
                o[ndt] = __builtin_amdgcn_mfma_f32_16x16x32_bf16(Pf, Vr[ks2][ndt], o[ndt], 0, 0, 0);
        }
#pragma unroll
        for (int ndt = 0; ndt < 2; ++ndt) {
            opk[ntQ][ndt][0] = pk2(o[ndt][0], o[ndt][1]);
            opk[ntQ][ndt][1] = pk2(o[ndt][2], o[ndt][3]);
        }
#pragma unroll
        for (int mtK = 0; mtK < 4; ++mtK) {
            bc0[mtK] = bn0[mtK];
            bc1[mtK] = bn1[mtK];
        }
    }

    __syncthreads();   // all waves done with XS reads / wave scratch
    // stage head outputs into OUTS (overlaps XS); head h -> cols [h*32, h*32+32)
#pragma unroll
    for (int mt = 0; mt < 4; ++mt)
#pragma unroll
        for (int n2 = 0; n2 < 2; ++n2)
#pragma unroll
            for (int jj = 0; jj < 2; ++jj) {
                u32 w = opk[mt][n2][jj];
                int row = mt * 16 + g * 4 + jj * 2;
                int colb = h * 32 + n2 * 16 + c;
                if (row < 49)     sm[row * 264 + colb] = (u16)(w & 0xffffu);
                if (row + 1 < 49) sm[(row + 1) * 264 + colb] = (u16)(w >> 16);
            }

    // prefetch proj ks=0 weight frags; they complete during the barrier drain
    s16x8 pf[2][2];
#pragma unroll
    for (int n = 0; n < 2; ++n)
        pf[0][n] = *(const s16x8*)&projwC[(((wv * 2 + n) * 8 + 0) * 64 + lane) * 8];
    __syncthreads();

    // ---- output projection: wave wv covers cols [wv*32, wv*32+32), dbuf weights ----
    f32x4 pacc[4][2];
#pragma unroll
    for (int mt = 0; mt < 4; ++mt)
#pragma unroll
        for (int n = 0; n < 2; ++n) pacc[mt][n] = f32x4{0.f, 0.f, 0.f, 0.f};
#pragma unroll
    for (int ks = 0; ks < 8; ++ks) {
        if (ks < 7) {
#pragma unroll
            for (int n = 0; n < 2; ++n)
                pf[(ks + 1) & 1][n] =
                    *(const s16x8*)&projwC[(((wv * 2 + n) * 8 + (ks + 1)) * 64 + lane) * 8];
        }
        s16x8 ao[4];
#pragma unroll
        for (int mt = 0; mt < 4; ++mt) {
            int row = mt * 16 + c; row = row > 48 ? 48 : row;
            ao[mt] = *(const s16x8*)&sm[row * 264 + ks * 32 + g * 8];
        }
#pragma unroll
        for (int n = 0; n < 2; ++n)
#pragma unroll
            for (int mt = 0; mt < 4; ++mt)
                pacc[mt][n] = __builtin_amdgcn_mfma_f32_16x16x32_bf16(ao[mt], pf[ks & 1][n], pacc[mt][n], 0, 0, 0);
    }
    float* ob = out + (size_t)b * 12544;
#pragma unroll
    for (int n = 0; n < 2; ++n) {
        int col = (wv * 2 + n) * 16 + c;
        float pb = proj_b[col];
#pragma unroll
        for (int mt = 0; mt < 4; ++mt)
#pragma unroll
            for (int j = 0; j < 4; ++j) {
                int row = mt * 16 + g * 4 + j;
                if (row < 49) ob[row * 256 + col] = pacc[mt][n][j] + pb;
            }
    }
}

extern "C" void kernel_launch(void* const* d_in, const int* in_sizes, int n_in,
                              void* d_out, int out_size, void* d_ws, size_t ws_size,
                              hipStream_t stream) {
    const float* x          = (const float*)d_in[0];
    const float* mask       = (const float*)d_in[1];
    const float* qkv_w      = (const float*)d_in[2];
    const float* qkv_b      = (const float*)d_in[3];
    const float* bias_table = (const float*)d_in[4];
    const float* proj_w     = (const float*)d_in[5];
    const float* proj_b     = (const float*)d_in[6];
    const int*   rel_index  = (const int*)d_in[7];

    u16* wqkvC2 = (u16*)d_ws;
    u16* projwC = (u16*)((char*)d_ws + WS_PROJW);
    u16* bmC2   = (u16*)((char*)d_ws + WS_BMC);

    prep<<<8192, 256, 0, stream>>>(qkv_w, proj_w, bias_table, rel_index, mask,
                                   wqkvC2, projwC, bmC2);
    swin_attn<<<2048, 512, 0, stream>>>(x, qkv_b, proj_b, wqkvC2, projwC, bmC2,
                                        (float*)d_out);
}

// Round 13
// 174.106 us; speedup vs baseline: 2.0302x; 2.0302x over previous
//
#include <hip/hip_runtime.h>

typedef float f32x4 __attribute__((ext_vector_type(4)));
typedef short s16x8 __attribute__((ext_vector_type(8)));
typedef unsigned int u32x4 __attribute__((ext_vector_type(4)));
typedef unsigned short u16;
typedef unsigned int u32;

#define QK_SCALE 0.17677669529663687f  // 32^-0.5
#define XSTR 266                       // XS/OUTS row stride (133 dw, odd -> <=2-way banks)
#define VSTR 76                        // VT row stride (38 dw -> <=2-way banks)

__device__ __forceinline__ u16 f2bf(float f) {
    unsigned u = __builtin_bit_cast(unsigned, f);
    u = (u + 0x7fffu + ((u >> 16) & 1u)) >> 16;
    return (u16)u;
}
__device__ __forceinline__ u32 pk2(float lo, float hi) {
    return (u32)f2bf(lo) | ((u32)f2bf(hi) << 16);
}

// C-frag(pair) -> operand-frag conversion:
// dst lane (c,g) elem e needs M[t=c][u=8g+e]; src lane (c, 2(g&1)+(e>>2)),
// utile=g>>1, j=e&3.  r0/r1 = packed (j0,j1)/(j2,j3) words per utile.
__device__ __forceinline__ s16x8 frag4(u32 r0u0, u32 r1u0, u32 r0u1, u32 r1u1,
                                       int aA, int aB, bool lo) {
    u32x4 w;
    u32 a, bq;
    a  = (u32)__builtin_amdgcn_ds_bpermute(aA, (int)r0u0);
    bq = (u32)__builtin_amdgcn_ds_bpermute(aA, (int)r0u1);
    w[0] = lo ? a : bq;
    a  = (u32)__builtin_amdgcn_ds_bpermute(aA, (int)r1u0);
    bq = (u32)__builtin_amdgcn_ds_bpermute(aA, (int)r1u1);
    w[1] = lo ? a : bq;
    a  = (u32)__builtin_amdgcn_ds_bpermute(aB, (int)r0u0);
    bq = (u32)__builtin_amdgcn_ds_bpermute(aB, (int)r0u1);
    w[2] = lo ? a : bq;
    a  = (u32)__builtin_amdgcn_ds_bpermute(aB, (int)r1u0);
    bq = (u32)__builtin_amdgcn_ds_bpermute(aB, (int)r1u1);
    w[3] = lo ? a : bq;
    return __builtin_bit_cast(s16x8, w);
}

// ---- workspace byte offsets ----
// wqkvC2: 196608 bf16 = 393216 B   [h8][f6 = t3*dt2][ks8][lane64][e8]  (A-frags of W for W·X^T)
// projwC:  65536 bf16 = 131072 B   [nt16][ks8][lane64][e8]
// bmC2  : 2097152 bf16 = 4 MB      [wi64][h8][ntQ4][mtK4][lane64][j4]  (bias+mask, St frag order)
#define WS_PROJW 393216
#define WS_BMC   524288

__global__ void prep(const float* __restrict__ qkv_w, const float* __restrict__ proj_w,
                     const float* __restrict__ bias_table, const int* __restrict__ rel_index,
                     const float* __restrict__ mask,
                     u16* __restrict__ wqkvC2, u16* __restrict__ projwC,
                     u16* __restrict__ bmC2) {
    int i = blockIdx.x * 256 + threadIdx.x;
    if (i < 196608) {                       // qkv weights as A-frags of W·X^T
        int e = i & 7, lane = (i >> 3) & 63, ks = (i >> 9) & 7, dt = (i >> 12) & 1;
        int i2 = i >> 13, t = i2 % 3, h = i2 / 3;
        int c = lane & 15, g = lane >> 4;
        wqkvC2[i] = f2bf(qkv_w[(t * 256 + h * 32 + dt * 16 + c) * 256 + ks * 32 + g * 8 + e]);
    }
    if (i < 65536) {                        // proj weights -> fragment order
        int e = i & 7, lane = (i >> 3) & 63, ks = (i >> 9) & 7, nt = (i >> 12) & 15;
        int c = lane & 15, g = lane >> 4;
        projwC[i] = f2bf(proj_w[(nt * 16 + c) * 256 + ks * 32 + g * 8 + e]);
    }
    {                                       // merged bias+mask, bf16, St C-frag order
        int j = i & 3, lane = (i >> 2) & 63, mtK = (i >> 8) & 3, ntQ = (i >> 10) & 3;
        int h = (i >> 12) & 7, wi = i >> 15;
        int c = lane & 15, g = lane >> 4;
        int q = ntQ * 16 + c, k = mtK * 16 + g * 4 + j;
        float v;
        if (k < 49) v = (q < 49) ? bias_table[rel_index[q * 49 + k] * 8 + h]
                                   + mask[wi * 2401 + q * 49 + k]
                                 : 0.f;
        else        v = -1e30f;             // pad-column mask folded in
        bmC2[i] = f2bf(v);
    }
}

// ---- LDS (u16 offsets), total 22762 u16 = 45,524 B -> 3 blocks/CU (LDS-wise) ----
// XS  : [0, 49*XSTR)  49 rows x 266  (x window, bf16)
// VT  : 49*XSTR + wv*32*VSTR, [d32][tok  VSTR] per wave
// OUTS: [0, 49*XSTR)  overlaps XS after barrier
__global__ __launch_bounds__(256, 3)
void swin_attn(const float* __restrict__ x,
               const float* __restrict__ qkv_b,
               const float* __restrict__ proj_b,
               const u16* __restrict__ wqkvC2,
               const u16* __restrict__ projwC,
               const u16* __restrict__ bmC2,
               float* __restrict__ out) {
    __shared__ __align__(16) u16 sm[22762];
    const int b = blockIdx.x, tid = threadIdx.x;
    const int wv = tid >> 6, lane = tid & 63, g = lane >> 4, c = lane & 15;
    const int wi = b & 63;
    const int VTb = 49 * XSTR + wv * 32 * VSTR;
    const float* xw = x + (size_t)b * 12544;

    // stage x window (bf16), rows 0..48
    for (int i = tid; i < 49 * 64; i += 256) {
        int row = i >> 6, q4 = i & 63;
        float4 v = ((const float4*)xw)[i];
        ushort4 s;
        s.x = f2bf(v.x); s.y = f2bf(v.y); s.z = f2bf(v.z); s.w = f2bf(v.w);
        *(ushort4*)&sm[row * XSTR + q4 * 4] = s;
    }
    __syncthreads();

    const int addrA = ((lane & 15) + ((lane & 16) << 1)) << 2;  // src lane c+32*(g&1)
    const int addrB = addrA + 64;                               // +16 lanes
    const bool lo = lane < 32;                                  // utile = g>>1
    const s16x8 zfrag = {0, 0, 0, 0, 0, 0, 0, 0};

    u32 opk[2][4][2][2];

#pragma unroll
    for (int hl = 0; hl < 2; ++hl) {
        const int h = wv * 2 + hl;

        // ---- QKV as W·X^T in two f-halves (acc 48 AGPR + wf 24 + Xf 16 live) ----
        u32 qp[4][2][2], kp[4][2][2];
#pragma unroll
        for (int half = 0; half < 2; ++half) {
            f32x4 acc[3][4];
#pragma unroll
            for (int f3 = 0; f3 < 3; ++f3)
#pragma unroll
                for (int tt = 0; tt < 4; ++tt) acc[f3][tt] = f32x4{0.f, 0.f, 0.f, 0.f};

            s16x8 wf[2][3];
#pragma unroll
            for (int f3 = 0; f3 < 3; ++f3)
                wf[0][f3] = *(const s16x8*)&wqkvC2[(((h * 6 + half * 3 + f3) * 8 + 0) * 64 + lane) * 8];
#pragma unroll
            for (int ks = 0; ks < 8; ++ks) {
                if (ks < 7) {
#pragma unroll
                    for (int f3 = 0; f3 < 3; ++f3)
                        wf[(ks + 1) & 1][f3] =
                            *(const s16x8*)&wqkvC2[(((h * 6 + half * 3 + f3) * 8 + (ks + 1)) * 64 + lane) * 8];
                }
                s16x8 Xf[4];
#pragma unroll
                for (int tt = 0; tt < 4; ++tt)
                    Xf[tt] = *(const s16x8*)&sm[(tt * 16 + c) * XSTR + ks * 32 + g * 8];
                if (c > 0) Xf[3] = zfrag;      // tokens 49..63 zero
#pragma unroll
                for (int f3 = 0; f3 < 3; ++f3)
#pragma unroll
                    for (int tt = 0; tt < 4; ++tt)
                        acc[f3][tt] = __builtin_amdgcn_mfma_f32_16x16x32_bf16(wf[ks & 1][f3], Xf[tt], acc[f3][tt], 0, 0, 0);
            }
            // bias, pack Qt/Kt to regs; Vt -> VT LDS
#pragma unroll
            for (int f3 = 0; f3 < 3; ++f3) {
                int f = half * 3 + f3;
                int t = f >> 1, dt = f & 1;
                f32x4 bv = *(const f32x4*)&qkv_b[t * 256 + h * 32 + dt * 16 + g * 4];
#pragma unroll
                for (int tt = 0; tt < 4; ++tt) {
                    float v0 = acc[f3][tt][0] + bv[0];
                    float v1 = acc[f3][tt][1] + bv[1];
                    float v2 = acc[f3][tt][2] + bv[2];
                    float v3 = acc[f3][tt][3] + bv[3];
                    if (t == 0) {
                        qp[tt][dt][0] = pk2(v0 * QK_SCALE, v1 * QK_SCALE);
                        qp[tt][dt][1] = pk2(v2 * QK_SCALE, v3 * QK_SCALE);
                    } else if (t == 1) {
                        kp[tt][dt][0] = pk2(v0, v1);
                        kp[tt][dt][1] = pk2(v2, v3);
                    } else {
                        sm[VTb + (dt * 16 + g * 4 + 0) * VSTR + tt * 16 + c] = f2bf(v0);
                        sm[VTb + (dt * 16 + g * 4 + 1) * VSTR + tt * 16 + c] = f2bf(v1);
                        sm[VTb + (dt * 16 + g * 4 + 2) * VSTR + tt * 16 + c] = f2bf(v2);
                        sm[VTb + (dt * 16 + g * 4 + 3) * VSTR + tt * 16 + c] = f2bf(v3);
                    }
                }
            }
        }

        // ---- Kf once (kp dies); qp kept for per-ntQ Qf; V stays in LDS ----
        s16x8 Kf[4];
#pragma unroll
        for (int mt = 0; mt < 4; ++mt)
            Kf[mt] = frag4(kp[mt][0][0], kp[mt][0][1], kp[mt][1][0], kp[mt][1][1], addrA, addrB, lo);

        // ---- streamed attention: per q-tile {bm load, Qf, St, softmax, pack, PV} ----
#pragma unroll
        for (int ntQ = 0; ntQ < 4; ++ntQ) {
            u32 bc0[4], bc1[4];
#pragma unroll
            for (int mtK = 0; mtK < 4; ++mtK) {
                const u32* bp = (const u32*)&bmC2[((((wi * 8 + h) * 4 + ntQ) * 4 + mtK) * 64 + lane) * 4];
                bc0[mtK] = bp[0];
                bc1[mtK] = bp[1];
            }
            s16x8 Qfc = frag4(qp[ntQ][0][0], qp[ntQ][0][1], qp[ntQ][1][0], qp[ntQ][1][1], addrA, addrB, lo);
            f32x4 lvc[4];
#pragma unroll
            for (int mtK = 0; mtK < 4; ++mtK) {
                f32x4 z = {0.f, 0.f, 0.f, 0.f};
                lvc[mtK] = __builtin_amdgcn_mfma_f32_16x16x32_bf16(Kf[mtK], Qfc, z, 0, 0, 0);
            }
            float m = -1e30f;
#pragma unroll
            for (int mtK = 0; mtK < 4; ++mtK) {
                u32 w0 = bc0[mtK], w1 = bc1[mtK];
                float b0 = __builtin_bit_cast(float, w0 << 16);
                float b1 = __builtin_bit_cast(float, w0 & 0xffff0000u);
                float b2 = __builtin_bit_cast(float, w1 << 16);
                float b3 = __builtin_bit_cast(float, w1 & 0xffff0000u);
                float v0 = lvc[mtK][0] + b0;
                float v1 = lvc[mtK][1] + b1;
                float v2 = lvc[mtK][2] + b2;
                float v3 = lvc[mtK][3] + b3;
                lvc[mtK][0] = v0; lvc[mtK][1] = v1;
                lvc[mtK][2] = v2; lvc[mtK][3] = v3;
                m = fmaxf(m, fmaxf(fmaxf(v0, v1), fmaxf(v2, v3)));
            }
            m = fmaxf(m, __shfl_xor(m, 16));
            m = fmaxf(m, __shfl_xor(m, 32));
            float s = 0.f;
#pragma unroll
            for (int mtK = 0; mtK < 4; ++mtK)
#pragma unroll
                for (int j = 0; j < 4; ++j) {
                    float e = __expf(lvc[mtK][j] - m);
                    lvc[mtK][j] = e;
                    s += e;
                }
            s += __shfl_xor(s, 16);
            s += __shfl_xor(s, 32);
            float is = 1.0f / s;
            u32 ppc[4][2];
#pragma unroll
            for (int mtK = 0; mtK < 4; ++mtK) {
                ppc[mtK][0] = pk2(lvc[mtK][0] * is, lvc[mtK][1] * is);
                ppc[mtK][1] = pk2(lvc[mtK][2] * is, lvc[mtK][3] * is);
            }
            // PV for this q-tile (V frags from LDS)
            f32x4 o[2] = {{0.f, 0.f, 0.f, 0.f}, {0.f, 0.f, 0.f, 0.f}};
#pragma unroll
            for (int ks2 = 0; ks2 < 2; ++ks2) {
                s16x8 Pf = frag4(ppc[2 * ks2][0], ppc[2 * ks2][1],
                                 ppc[2 * ks2 + 1][0], ppc[2 * ks2 + 1][1], addrA, addrB, lo);
#pragma unroll
                for (int ndt = 0; ndt < 2; ++ndt) {
                    s16x8 Vf = *(const s16x8*)&sm[VTb + (ndt * 16 + c) * VSTR + ks2 * 32 + g * 8];
                    o[ndt] = __builtin_amdgcn_mfma_f32_16x16x32_bf16(Pf, Vf, o[ndt], 0, 0, 0);
                }
            }
#pragma unroll
            for (int ndt = 0; ndt < 2; ++ndt) {
                opk[hl][ntQ][ndt][0] = pk2(o[ndt][0], o[ndt][1]);
                opk[hl][ntQ][ndt][1] = pk2(o[ndt][2], o[ndt][3]);
            }
        }
    }

    __syncthreads();   // all waves done with XS reads / wave scratch
    // stage head outputs into OUTS (overlaps XS)
#pragma unroll
    for (int hl = 0; hl < 2; ++hl)
#pragma unroll
        for (int mt = 0; mt < 4; ++mt)
#pragma unroll
            for (int n2 = 0; n2 < 2; ++n2)
#pragma unroll
                for (int jj = 0; jj < 2; ++jj) {
                    u32 w = opk[hl][mt][n2][jj];
                    int row = mt * 16 + g * 4 + jj * 2;
                    int colb = (wv * 2 + hl) * 32 + n2 * 16 + c;
                    if (row < 49)     sm[row * XSTR + colb] = (u16)(w & 0xffffu);
                    if (row + 1 < 49) sm[(row + 1) * XSTR + colb] = (u16)(w >> 16);
                }

    // prefetch proj ks=0 weight frags; they complete during the barrier drain
    s16x8 pf[2][4];
#pragma unroll
    for (int n = 0; n < 4; ++n)
        pf[0][n] = *(const s16x8*)&projwC[(((wv * 4 + n) * 8 + 0) * 64 + lane) * 8];
    __syncthreads();

    // ---- output projection: wave wv covers cols [wv*64, wv*64+64), dbuf weights ----
    f32x4 pacc[4][4];
#pragma unroll
    for (int mt = 0; mt < 4; ++mt)
#pragma unroll
        for (int n = 0; n < 4; ++n) pacc[mt][n] = f32x4{0.f, 0.f, 0.f, 0.f};
#pragma unroll
    for (int ks = 0; ks < 8; ++ks) {
        if (ks < 7) {
#pragma unroll
            for (int n = 0; n < 4; ++n)
                pf[(ks + 1) & 1][n] =
                    *(const s16x8*)&projwC[(((wv * 4 + n) * 8 + (ks + 1)) * 64 + lane) * 8];
        }
        s16x8 ao[4];
#pragma unroll
        for (int mt = 0; mt < 4; ++mt) {
            int row = mt * 16 + c; row = row > 48 ? 48 : row;
            ao[mt] = *(const s16x8*)&sm[row * XSTR + ks * 32 + g * 8];
        }
#pragma unroll
        for (int n = 0; n < 4; ++n)
#pragma unroll
            for (int mt = 0; mt < 4; ++mt)
                pacc[mt][n] = __builtin_amdgcn_mfma_f32_16x16x32_bf16(ao[mt], pf[ks & 1][n], pacc[mt][n], 0, 0, 0);
    }
    float* ob = out + (size_t)b * 12544;
#pragma unroll
    for (int n = 0; n < 4; ++n) {
        int col = (wv * 4 + n) * 16 + c;
        float pb = proj_b[col];
#pragma unroll
        for (int mt = 0; mt < 4; ++mt)
#pragma unroll
            for (int j = 0; j < 4; ++j) {
                int row = mt * 16 + g * 4 + j;
                if (row < 49) ob[row * 256 + col] = pacc[mt][n][j] + pb;
            }
    }
}

extern "C" void kernel_launch(void* const* d_in, const int* in_sizes, int n_in,
                              void* d_out, int out_size, void* d_ws, size_t ws_size,
                              hipStream_t stream) {
    const float* x          = (const float*)d_in[0];
    const float* mask       = (const float*)d_in[1];
    const float* qkv_w      = (const float*)d_in[2];
    const float* qkv_b      = (const float*)d_in[3];
    const float* bias_table = (const float*)d_in[4];
    const float* proj_w     = (const float*)d_in[5];
    const float* proj_b     = (const float*)d_in[6];
    const int*   rel_index  = (const int*)d_in[7];

    u16* wqkvC2 = (u16*)d_ws;
    u16* projwC = (u16*)((char*)d_ws + WS_PROJW);
    u16* bmC2   = (u16*)((char*)d_ws + WS_BMC);

    prep<<<8192, 256, 0, stream>>>(qkv_w, proj_w, bias_table, rel_index, mask,
                                   wqkvC2, projwC, bmC2);
    swin_attn<<<2048, 256, 0, stream>>>(x, qkv_b, proj_b, wqkvC2, projwC, bmC2,
                                        (float*)d_out);
}